// Round 6
// 612.304 us; speedup vs baseline: 1.0411x; 1.0411x over previous
//
#include <hip/hip_runtime.h>

// Problem constants (match reference)
constexpr int   S_     = 16;
constexpr int   N_     = 8192;
constexpr int   NSRC   = 10000;
constexpr int   MINDST = 10000;
constexpr float TDMAX  = 5000.0f;

typedef float f4 __attribute__((ext_vector_type(4)));

__device__ __forceinline__ float wave_reduce_sum(float v) {
#pragma unroll
    for (int off = 32; off > 0; off >>= 1)
        v += __shfl_xor(v, off, 64);
    return v;
}

// psi * (log1p(exp(-g_psi)) + g_psi), g = dot + b + alpha*exp(-w_t * td/TDMAX)
__device__ __forceinline__ float hawkes(float gdot, float td,
                                        float b, float psi, float alpha, float wt) {
    float g  = gdot + b + alpha * expf(-wt * (td * (1.0f / TDMAX)));
    float gp = g / (psi + 1e-7f);
    gp = fminf(fmaxf(gp, -75.0f), 75.0f);
    return psi * (log1pf(expf(-gp)) + gp);
}

// USE_ATOMIC=false: write one float2 partial per block into ws (no atomics).
// USE_ATOMIC=true : legacy atomicAdd epilogue (fallback when ws too small).
template <bool USE_ATOMIC>
__global__ __launch_bounds__(256) void decoder_stage1(
    const float* __restrict__ emb,            // (20000, 256)
    const int*   __restrict__ assoc,          // (20000,)
    const int*   __restrict__ src,            // (N,)
    const int*   __restrict__ dst,            // (N,)
    const float* __restrict__ last_update,    // (20000,)
    const float* __restrict__ cur_time,       // (N,)
    const float* __restrict__ u_non,          // (S*N, 256)
    const float* __restrict__ v_non,          // (S*N, 256)
    const float* __restrict__ last_time_pos,  // (N,)
    const float* __restrict__ td_step,        // (S, N)
    const float* __restrict__ accu,           // (NSRC, NSRC)
    const float* __restrict__ W,              // (1, 512)
    const float* __restrict__ b_p,
    const float* __restrict__ psi_p,
    const float* __restrict__ alpha_p,
    const float* __restrict__ wt_p,
    float2* __restrict__ partial,             // (N/4,) block partials (ws path)
    float*  __restrict__ out)                 // atomic path target
{
    const int wave = threadIdx.x >> 6;        // 4 waves / block
    const int lane = threadIdx.x & 63;
    const int i    = (blockIdx.x << 2) + wave; // event index; grid = N/4 exactly

    // Per-lane weight fragment: lane holds W[4l..4l+3] (Wu) and W[256+4l..] (Wv)
    const f4* __restrict__ W4 = (const f4*)W;
    const f4 wu = W4[lane];
    const f4 wv = W4[64 + lane];
    const float b0    = b_p[0];
    const float psi   = psi_p[0];
    const float alpha = alpha_p[0];
    const float wt    = wt_p[0];

    // Small per-event scalars (wave-uniform addresses -> single transaction)
    const int si = src[i];
    const int di = dst[i];
    const int as = assoc[si];
    const int ad = assoc[di];
    // Random-gather from the 400 MB accu table: issue EARLY (unconditional),
    // so its ~900-cycle HBM miss hides under the 32 KB survival stream below
    // instead of sitting exposed on the critical path after the loop.
    const float accu_v = accu[(size_t)si * NSRC + (di - MINDST)];
    const float lum  = fmaxf(last_update[as], last_update[ad]);
    const float ltp  = last_time_pos[i];
    const float ct   = cur_time[i];
    const float t_uv = fmaxf(lum, ltp);
    const float td_uv = ct - t_uv;

    // lambda_uv: dot(z_src, Wu) + dot(z_dst, Wv)
    const f4* __restrict__ Z4 = (const f4*)emb;
    const f4 zs = Z4[(size_t)as * 64 + lane];
    const f4 zd = Z4[(size_t)ad * 64 + lane];
    float d = zs.x * wu.x + zs.y * wu.y + zs.z * wu.z + zs.w * wu.w
            + zd.x * wv.x + zd.y * wv.y + zd.z * wv.z + zd.w * wv.w;
    d = wave_reduce_sum(d);
    const float lam_uv = hawkes(d, td_uv, b0, psi, alpha, wt);
    const float loss_lambda = -logf(lam_uv + 1e-7f);

    // survival terms: 16 rows p = s*N + i (coalesced 1 KB/wave per stream).
    // Single-use streams -> nontemporal (protect emb/accu lines in L2/L3).
    const f4* __restrict__ U4 = (const f4*)u_non;
    const f4* __restrict__ V4 = (const f4*)v_non;
    float lam_sum = 0.0f;
#pragma unroll 4
    for (int s = 0; s < S_; ++s) {
        const size_t p = (size_t)s * N_ + i;
        const f4 uu = __builtin_nontemporal_load(&U4[p * 64 + lane]);
        const f4 vv = __builtin_nontemporal_load(&V4[p * 64 + lane]);
        float dd = uu.x * wu.x + uu.y * wu.y + uu.z * wu.z + uu.w * wu.w
                 + vv.x * wv.x + vv.y * wv.y + vv.z * wv.z + vv.w * wv.w;
        dd = wave_reduce_sum(dd);
        lam_sum += hawkes(dd, td_step[p] * td_uv, b0, psi, alpha, wt);
    }
    float loss_surv = lam_sum * (1.0f / S_) * td_uv;
    if (ltp >= lum) loss_surv += accu_v;

    // Block reduce (4 waves): one float2 per block, no global atomics
    // (4096 same-address device-scope atomicAdds across 8 XCDs serialize
    //  at the coherence point -- suspected ~90 us tail in the 637 us run).
    __shared__ float s_ll[4], s_sv[4];
    if (lane == 0) { s_ll[wave] = loss_lambda; s_sv[wave] = loss_surv; }
    __syncthreads();
    if (threadIdx.x == 0) {
        const float a = s_ll[0] + s_ll[1] + s_ll[2] + s_ll[3];
        const float c = s_sv[0] + s_sv[1] + s_sv[2] + s_sv[3];
        if (USE_ATOMIC) {
            atomicAdd(&out[0], a * (1.0f / N_));
            atomicAdd(&out[1], c * (1.0f / N_));
        } else {
            float2 pr; pr.x = a; pr.y = c;
            partial[blockIdx.x] = pr;
        }
    }
}

// Deterministic final reduce: 2048 float2 partials -> out[0], out[1].
// Fully overwrites d_out, so the poisoned output needs no memset on this path.
__global__ __launch_bounds__(256) void decoder_stage2(
    const float2* __restrict__ partial, float* __restrict__ out)
{
    float a = 0.0f, c = 0.0f;
    for (int k = threadIdx.x; k < N_ / 4; k += 256) {
        const float2 q = partial[k];
        a += q.x; c += q.y;
    }
    a = wave_reduce_sum(a);
    c = wave_reduce_sum(c);
    __shared__ float sa[4], sc[4];
    const int wave = threadIdx.x >> 6;
    const int lane = threadIdx.x & 63;
    if (lane == 0) { sa[wave] = a; sc[wave] = c; }
    __syncthreads();
    if (threadIdx.x == 0) {
        out[0] = (sa[0] + sa[1] + sa[2] + sa[3]) * (1.0f / N_);
        out[1] = (sc[0] + sc[1] + sc[2] + sc[3]) * (1.0f / N_);
    }
}

extern "C" void kernel_launch(void* const* d_in, const int* in_sizes, int n_in,
                              void* d_out, int out_size, void* d_ws, size_t ws_size,
                              hipStream_t stream) {
    const float* emb           = (const float*)d_in[0];
    const int*   assoc         = (const int*)  d_in[1];
    const int*   src           = (const int*)  d_in[2];
    const int*   dst           = (const int*)  d_in[3];
    const float* last_update   = (const float*)d_in[4];
    const float* cur_time      = (const float*)d_in[5];
    const float* u_non         = (const float*)d_in[6];
    const float* v_non         = (const float*)d_in[7];
    const float* last_time_pos = (const float*)d_in[8];
    const float* td_step       = (const float*)d_in[9];
    const float* accu          = (const float*)d_in[10];
    const float* W             = (const float*)d_in[11];
    const float* b_p           = (const float*)d_in[12];
    const float* psi_p         = (const float*)d_in[13];
    const float* alpha_p       = (const float*)d_in[14];
    const float* wt_p          = (const float*)d_in[15];
    float* out = (float*)d_out;

    const size_t need = (size_t)(N_ / 4) * sizeof(float2);  // 16 KB
    if (d_ws != nullptr && ws_size >= need) {
        // Two-stage deterministic reduction (no atomics, no output memset).
        float2* partial = (float2*)d_ws;
        decoder_stage1<false><<<N_ / 4, 256, 0, stream>>>(
            emb, assoc, src, dst, last_update, cur_time, u_non, v_non,
            last_time_pos, td_step, accu, W, b_p, psi_p, alpha_p, wt_p,
            partial, out);
        decoder_stage2<<<1, 256, 0, stream>>>(partial, out);
    } else {
        // Fallback: atomic epilogue (d_out poisoned -> zero it first).
        hipMemsetAsync(out, 0, 2 * sizeof(float), stream);
        decoder_stage1<true><<<N_ / 4, 256, 0, stream>>>(
            emb, assoc, src, dst, last_update, cur_time, u_non, v_non,
            last_time_pos, td_step, accu, W, b_p, psi_p, alpha_p, wt_p,
            nullptr, out);
    }
}